// Round 1
// baseline (228.905 us; speedup 1.0000x reference)
//
#include <hip/hip_runtime.h>
#include <hip/hip_bf16.h>

// Head attention: B=16, T=2048, C=512(n_embd), H=64(head)
// out[b,t,h] = softmax_causal( (x@Wq)(x@Wk)^T * C^-0.5 ) @ (x@Wv)
// end-token mask never triggers (idx in [0,32000), END=32000) but is implemented.

#define B_ 16
#define T_ 2048
#define C_ 512
#define H_ 64
#define LOG2E 1.4426950408889634f

typedef __attribute__((ext_vector_type(4))) float f32x4;
typedef __attribute__((ext_vector_type(8))) short bf16x8;
typedef __attribute__((ext_vector_type(4))) short bf16x4;

__device__ inline unsigned short f2bf(float f) {
    unsigned int u = __builtin_bit_cast(unsigned int, f);
    u += 0x7fff + ((u >> 16) & 1);   // RNE
    return (unsigned short)(u >> 16);
}

__device__ inline f32x4 mfma16(bf16x8 a, bf16x8 b, f32x4 c) {
    return __builtin_amdgcn_mfma_f32_16x16x32_bf16(a, b, c, 0, 0, 0);
}

// ---------------------------------------------------------------------------
// prep: Wt[n][k] = W[k][n] as bf16 (n: 0-63 K, 64-127 Q (x scale), 128-191 V)
//       block 384: init first_end[b] = T
// ---------------------------------------------------------------------------
__global__ void prep_kernel(const float* __restrict__ Wk, const float* __restrict__ Wq,
                            const float* __restrict__ Wv, unsigned short* __restrict__ Wt,
                            int* __restrict__ fe) {
    if (blockIdx.x == 384) {
        if (threadIdx.x < B_) fe[threadIdx.x] = T_;
        return;
    }
    int id = blockIdx.x * 256 + threadIdx.x;     // [0, 192*512)
    int n = id >> 9, k = id & 511;
    int mtx = n >> 6, nl = n & 63;
    const float* W = (mtx == 0) ? Wk : ((mtx == 1) ? Wq : Wv);
    float v = W[k * 64 + nl];
    if (mtx == 1) v *= 0.04419417382415922f;     // 1/sqrt(512) folded into Q
    Wt[n * 512 + k] = f2bf(v);
}

// ---------------------------------------------------------------------------
// scan_end: first_end[b] = min position with idx==END (atomicMin vs init T)
// ---------------------------------------------------------------------------
__global__ void scan_kernel(const int* __restrict__ idx, int* __restrict__ fe) {
    int i = blockIdx.x * 256 + threadIdx.x;      // [0, 32768)
    if (idx[i] == 32000) atomicMin(&fe[i >> 11], i & 2047);
}

// ---------------------------------------------------------------------------
// qkv: fused projections. Block = 64 tokens (4 waves x 16 rows), N=192 full.
//   A-frag direct from global x (fp32 -> bf16); B-frag direct from Wt (L2-hot).
//   Writes: Q,K row-major [tok][h] bf16; V transposed [b][h][t] bf16.
// ---------------------------------------------------------------------------
__global__ __launch_bounds__(256) void qkv_kernel(
        const float* __restrict__ x, const unsigned short* __restrict__ Wt,
        unsigned short* __restrict__ Qm, unsigned short* __restrict__ Km,
        unsigned short* __restrict__ Vt) {
    int tid = threadIdx.x;
    int wave = tid >> 6, lane = tid & 63;
    int m16 = lane & 15, quad = lane >> 4;
    long row0 = (long)blockIdx.x * 64;
    long arow = row0 + wave * 16 + m16;          // A-frag token row (m = lane&15)
    const float* xr = x + arow * C_;

    f32x4 acc[12];
#pragma unroll
    for (int i = 0; i < 12; i++) acc[i] = (f32x4){0.f, 0.f, 0.f, 0.f};

    for (int kb = 0; kb < C_; kb += 32) {
        const f32x4* xp = (const f32x4*)(xr + kb + quad * 8);
        f32x4 a0 = xp[0], a1 = xp[1];
        bf16x8 av;
#pragma unroll
        for (int j = 0; j < 4; j++) av[j] = (short)f2bf(a0[j]);
#pragma unroll
        for (int j = 0; j < 4; j++) av[4 + j] = (short)f2bf(a1[j]);
#pragma unroll
        for (int nt = 0; nt < 12; nt++) {
            bf16x8 bv = *(const bf16x8*)&Wt[(nt * 16 + m16) * C_ + kb + quad * 8];
            acc[nt] = mfma16(av, bv, acc[nt]);
        }
    }

    // Epilogue. C-layout: col(feature)=lane&15, row(token)=quad*4+reg.
    long crow = row0 + wave * 16 + quad * 4;
#pragma unroll
    for (int nt = 0; nt < 4; nt++) {             // K features 0-63
        int h = nt * 16 + m16;
#pragma unroll
        for (int r = 0; r < 4; r++) Km[(crow + r) * 64 + h] = f2bf(acc[nt][r]);
    }
#pragma unroll
    for (int nt = 4; nt < 8; nt++) {             // Q (pre-scaled)
        int h = (nt - 4) * 16 + m16;
#pragma unroll
        for (int r = 0; r < 4; r++) Qm[(crow + r) * 64 + h] = f2bf(acc[nt][r]);
    }
    int b = (int)(crow >> 11), tl = (int)(crow & 2047);
#pragma unroll
    for (int nt = 8; nt < 12; nt++) {            // V -> Vt[b][h][t], 4 consecutive t
        int h = (nt - 8) * 16 + m16;
        bf16x4 pk;
#pragma unroll
        for (int r = 0; r < 4; r++) pk[r] = (short)f2bf(acc[nt][r]);
        *(bf16x4*)&Vt[((long)b * 64 + h) * T_ + tl] = pk;
    }
}

// ---------------------------------------------------------------------------
// attn: flash attention, causal. Block = 64 q rows (wave owns 16), BN=64 keys.
//   LDS: K[64][64], Vt[64][64], P[wave][16][64], all XOR-swizzled (k ^ (row&7)*8)
//   so B-frag/A-frag ds_read_b128 are bank-conflict-free.
// ---------------------------------------------------------------------------
__global__ __launch_bounds__(256) void attn_kernel(
        const unsigned short* __restrict__ Qm, const unsigned short* __restrict__ Km,
        const unsigned short* __restrict__ Vt, const int* __restrict__ fe,
        float* __restrict__ out) {
    __shared__ __align__(16) unsigned short Klds[64 * 64];
    __shared__ __align__(16) unsigned short Vlds[64 * 64];
    __shared__ __align__(16) unsigned short Plds[4][16 * 64];

    int qt = blockIdx.x;                         // q tile [0,32)
    int b = blockIdx.y;
    int tid = threadIdx.x, wave = tid >> 6, lane = tid & 63;
    int m16 = lane & 15, quad = lane >> 4;
    int row0 = qt * 64;
    long bT = (long)b * T_;

    // Q A-frags (held in registers whole kernel): lane m=lane&15, k=quad*8+j
    const unsigned short* qp = Qm + (bT + row0 + wave * 16 + m16) * 64;
    bf16x8 qf0 = *(const bf16x8*)(qp + quad * 8);
    bf16x8 qf1 = *(const bf16x8*)(qp + 32 + quad * 8);

    f32x4 o[4];
#pragma unroll
    for (int h = 0; h < 4; h++) o[h] = (f32x4){0.f, 0.f, 0.f, 0.f};
    float mi[4], li[4];
#pragma unroll
    for (int r = 0; r < 4; r++) { mi[r] = -INFINITY; li[r] = 0.f; }
    int qloc = row0 + wave * 16 + quad * 4;      // query pos of reg 0 (C-layout row)

    for (int kt = 0; kt <= qt; kt++) {
        __syncthreads();                         // prior-iter LDS reads done
        // ---- stage K tile [key][dim] and V tile [dim][key] into LDS, swizzled
#pragma unroll
        for (int cc = 0; cc < 2; cc++) {
            int c = tid + cc * 256;              // 512 chunks of 16B each
            int row = c >> 3, k8 = (c & 7) * 8;
            int sw = k8 ^ ((row & 7) * 8);
            *(bf16x8*)&Klds[row * 64 + sw] =
                *(const bf16x8*)&Km[(bT + kt * 64 + row) * 64 + k8];
            *(bf16x8*)&Vlds[row * 64 + sw] =
                *(const bf16x8*)&Vt[((long)b * 64 + row) * T_ + kt * 64 + k8];
        }
        __syncthreads();

        // ---- S = Q K^T (16 x 64 per wave), 4 n-subtiles x 2 k-halves
        f32x4 s[4];
#pragma unroll
        for (int ns = 0; ns < 4; ns++) {
            int krow = ns * 16 + m16;
            int swz = (krow & 7) * 8;
            bf16x8 kf0 = *(const bf16x8*)&Klds[krow * 64 + ((quad * 8) ^ swz)];
            bf16x8 kf1 = *(const bf16x8*)&Klds[krow * 64 + ((32 + quad * 8) ^ swz)];
            f32x4 z = (f32x4){0.f, 0.f, 0.f, 0.f};
            z = mfma16(qf0, kf0, z);
            z = mfma16(qf1, kf1, z);
            s[ns] = z;
        }

        bool diag = (kt == qt);
        float alpha[4];
#pragma unroll
        for (int r = 0; r < 4; r++) {
            int qpos = qloc + r;
            if (diag) {
#pragma unroll
                for (int ns = 0; ns < 4; ns++) {
                    int n = kt * 64 + ns * 16 + m16;
                    if (n > qpos) s[ns][r] = -INFINITY;
                }
            }
            float mx = fmaxf(fmaxf(s[0][r], s[1][r]), fmaxf(s[2][r], s[3][r]));
            mx = fmaxf(mx, mi[r]);
#pragma unroll
            for (int off = 1; off < 16; off <<= 1)
                mx = fmaxf(mx, __shfl_xor(mx, off));
            alpha[r] = exp2f((mi[r] - mx) * LOG2E);
            mi[r] = mx;
            float rs = 0.f;
#pragma unroll
            for (int ns = 0; ns < 4; ns++) {
                float p = exp2f((s[ns][r] - mx) * LOG2E);
                s[ns][r] = p;
                rs += p;
            }
#pragma unroll
            for (int off = 1; off < 16; off <<= 1)
                rs += __shfl_xor(rs, off);
            li[r] = li[r] * alpha[r] + rs;
#pragma unroll
            for (int h = 0; h < 4; h++) o[h][r] *= alpha[r];
        }

        // ---- P -> LDS (C-layout -> A-layout transform), own-wave region
        unsigned short* pw = Plds[wave];
#pragma unroll
        for (int ns = 0; ns < 4; ns++)
#pragma unroll
            for (int r = 0; r < 4; r++) {
                int mrow = quad * 4 + r;
                int n = ns * 16 + m16;
                pw[mrow * 64 + (n ^ ((mrow & 7) * 8))] = f2bf(s[ns][r]);
            }

        // ---- O += P V : A-frags from Plds, B-frags from Vlds
        int aswz = (m16 & 7) * 8;
        bf16x8 pa0 = *(const bf16x8*)&pw[m16 * 64 + ((quad * 8) ^ aswz)];
        bf16x8 pa1 = *(const bf16x8*)&pw[m16 * 64 + ((32 + quad * 8) ^ aswz)];
#pragma unroll
        for (int hs = 0; hs < 4; hs++) {
            int vrow = hs * 16 + m16;
            int vswz = (vrow & 7) * 8;
            bf16x8 vb0 = *(const bf16x8*)&Vlds[vrow * 64 + ((quad * 8) ^ vswz)];
            bf16x8 vb1 = *(const bf16x8*)&Vlds[vrow * 64 + ((32 + quad * 8) ^ vswz)];
            o[hs] = mfma16(pa0, vb0, o[hs]);
            o[hs] = mfma16(pa1, vb1, o[hs]);
        }
    }

    // ---- epilogue: out[b][t][h] fp32; dead rows (t >= first_end) -> NaN (ref)
    int feb = fe[b];
#pragma unroll
    for (int r = 0; r < 4; r++) {
        int t = qloc + r;
        float inv = 1.0f / li[r];
        bool dead = (t >= feb);
#pragma unroll
        for (int hs = 0; hs < 4; hs++) {
            float val = dead ? __builtin_nanf("") : o[hs][r] * inv;
            out[(bT + t) * 64 + hs * 16 + m16] = val;
        }
    }
}

// ---------------------------------------------------------------------------
extern "C" void kernel_launch(void* const* d_in, const int* in_sizes, int n_in,
                              void* d_out, int out_size, void* d_ws, size_t ws_size,
                              hipStream_t stream) {
    const float* x  = (const float*)d_in[0];
    const float* Wk = (const float*)d_in[1];
    const float* Wq = (const float*)d_in[2];
    const float* Wv = (const float*)d_in[3];
    const int* idx  = (const int*)d_in[4];
    float* out = (float*)d_out;

    char* ws = (char*)d_ws;
    int* fe            = (int*)ws;                                 //    64 B
    unsigned short* Wt = (unsigned short*)(ws + 1024);             //  192 KiB
    unsigned short* Qm = (unsigned short*)(ws + 262144);           //    4 MiB
    unsigned short* Km = (unsigned short*)(ws + 262144 + 4194304); //    4 MiB
    unsigned short* Vt = (unsigned short*)(ws + 262144 + 8388608); //    4 MiB
    // total ws needed: ~12.3 MiB

    prep_kernel<<<385, 256, 0, stream>>>(Wk, Wq, Wv, Wt, fe);
    scan_kernel<<<128, 256, 0, stream>>>(idx, fe);
    qkv_kernel<<<512, 256, 0, stream>>>(x, Wt, Qm, Km, Vt);
    dim3 g(32, 16);
    attn_kernel<<<g, 256, 0, stream>>>(Qm, Km, Vt, fe, out);
}

// Round 2
// 176.789 us; speedup vs baseline: 1.2948x; 1.2948x over previous
//
#include <hip/hip_runtime.h>
#include <hip/hip_bf16.h>

// Head attention: B=16, T=2048, C=512(n_embd), H=64(head)
// out[b,t,h] = softmax_causal( (x@Wq)(x@Wk)^T * C^-0.5 ) @ (x@Wv)

#define B_ 16
#define T_ 2048
#define C_ 512
#define LOG2E 1.4426950408889634f

typedef __attribute__((ext_vector_type(4))) float f32x4;
typedef __attribute__((ext_vector_type(8))) short bf16x8;

__device__ inline unsigned short f2bf(float f) {
    unsigned int u = __builtin_bit_cast(unsigned int, f);
    u += 0x7fff + ((u >> 16) & 1);   // RNE
    return (unsigned short)(u >> 16);
}

__device__ inline f32x4 mfma16(bf16x8 a, bf16x8 b, f32x4 c) {
    return __builtin_amdgcn_mfma_f32_16x16x32_bf16(a, b, c, 0, 0, 0);
}

// ---------------------------------------------------------------------------
// prep: Wt[n][k] = W[k][n] as bf16 (n: 0-63 K, 64-127 Q (x scale), 128-191 V)
// ---------------------------------------------------------------------------
__global__ void prep_kernel(const float* __restrict__ Wk, const float* __restrict__ Wq,
                            const float* __restrict__ Wv, unsigned short* __restrict__ Wt,
                            int* __restrict__ fe) {
    if (blockIdx.x == 384) {
        if (threadIdx.x < B_) fe[threadIdx.x] = T_;
        return;
    }
    int id = blockIdx.x * 256 + threadIdx.x;
    int n = id >> 9, k = id & 511;
    int mtx = n >> 6, nl = n & 63;
    const float* W = (mtx == 0) ? Wk : ((mtx == 1) ? Wq : Wv);
    float v = W[k * 64 + nl];
    if (mtx == 1) v *= 0.04419417382415922f;     // 1/sqrt(512) folded into Q
    Wt[n * 512 + k] = f2bf(v);
}

__global__ void scan_kernel(const int* __restrict__ idx, int* __restrict__ fe) {
    int i = blockIdx.x * 256 + threadIdx.x;
    if (idx[i] == 32000) atomicMin(&fe[i >> 11], i & 2047);
}

// ---------------------------------------------------------------------------
// qkv: 64 tokens/block, n-split: wave w owns n-tiles {w, w+4, w+8} (K/Q/V
// feature block 16w..16w+16). x + Wt chunks staged in LDS (coalesced,
// XOR-swizzled), register prefetch of next chunk. V computed TRANSPOSED by
// swapping MFMA operands (D[m=feat][n=tok]). All global stores coalesced b128
// via LDS epilogue.
// ---------------------------------------------------------------------------
__global__ __launch_bounds__(256) void qkv_kernel(
        const float* __restrict__ x, const unsigned short* __restrict__ Wt,
        unsigned short* __restrict__ Qm, unsigned short* __restrict__ Km,
        unsigned short* __restrict__ Vt) {
    __shared__ __align__(16) char smem[32768];
    unsigned short* xs  = (unsigned short*)smem;            // [64][64] swizzled
    unsigned short* wsh = (unsigned short*)(smem + 8192);   // [192][64] swizzled
    unsigned short* co  = (unsigned short*)smem;            // [64][136] K|Q epilogue
    unsigned short* vco = (unsigned short*)(smem + 17408);  // [4][16][72] V epilogue

    int tid = threadIdx.x, wave = tid >> 6, lane = tid & 63;
    int m16 = lane & 15, quad = lane >> 4;
    int row0 = blockIdx.x * 64;

    int xrow[2], xcol[2], wrow[6], wcol[6];
#pragma unroll
    for (int i = 0; i < 2; i++) { int u = tid + i * 256; xrow[i] = u >> 3; xcol[i] = (u & 7) * 8; }
#pragma unroll
    for (int i = 0; i < 6; i++) { int u = tid + i * 256; wrow[i] = u >> 3; wcol[i] = (u & 7) * 8; }

    f32x4 xa[2][2]; bf16x8 wr[6];
#pragma unroll
    for (int i = 0; i < 2; i++) {
        const f32x4* p = (const f32x4*)(x + (long)(row0 + xrow[i]) * C_ + xcol[i]);
        xa[i][0] = p[0]; xa[i][1] = p[1];
    }
#pragma unroll
    for (int i = 0; i < 6; i++) wr[i] = *(const bf16x8*)&Wt[wrow[i] * C_ + wcol[i]];

    f32x4 ka[4], qa[4], va[4];
#pragma unroll
    for (int i = 0; i < 4; i++) {
        ka[i] = (f32x4){0.f, 0.f, 0.f, 0.f};
        qa[i] = (f32x4){0.f, 0.f, 0.f, 0.f};
        va[i] = (f32x4){0.f, 0.f, 0.f, 0.f};
    }

    for (int kb = 0; kb < C_; kb += 64) {
        __syncthreads();                         // prior compute LDS reads done
#pragma unroll
        for (int i = 0; i < 2; i++) {
            bf16x8 t;
#pragma unroll
            for (int j = 0; j < 4; j++) t[j] = (short)f2bf(xa[i][0][j]);
#pragma unroll
            for (int j = 0; j < 4; j++) t[4 + j] = (short)f2bf(xa[i][1][j]);
            *(bf16x8*)&xs[xrow[i] * 64 + (xcol[i] ^ ((xrow[i] & 7) * 8))] = t;
        }
#pragma unroll
        for (int i = 0; i < 6; i++)
            *(bf16x8*)&wsh[wrow[i] * 64 + (wcol[i] ^ ((wrow[i] & 7) * 8))] = wr[i];
        int kn = kb + 64;
        if (kn < C_) {                           // prefetch next chunk into regs
#pragma unroll
            for (int i = 0; i < 2; i++) {
                const f32x4* p = (const f32x4*)(x + (long)(row0 + xrow[i]) * C_ + kn + xcol[i]);
                xa[i][0] = p[0]; xa[i][1] = p[1];
            }
#pragma unroll
            for (int i = 0; i < 6; i++) wr[i] = *(const bf16x8*)&Wt[wrow[i] * C_ + kn + wcol[i]];
        }
        __syncthreads();
#pragma unroll
        for (int ks = 0; ks < 2; ks++) {
            int ko = ks * 32 + quad * 8;
            bf16x8 xf[4];
#pragma unroll
            for (int mt = 0; mt < 4; mt++) {
                int ar = mt * 16 + m16;
                xf[mt] = *(const bf16x8*)&xs[ar * 64 + (ko ^ ((ar & 7) * 8))];
            }
            int kr = wave * 16 + m16, qr = 64 + wave * 16 + m16, vr = 128 + wave * 16 + m16;
            bf16x8 wk = *(const bf16x8*)&wsh[kr * 64 + (ko ^ ((kr & 7) * 8))];
            bf16x8 wq = *(const bf16x8*)&wsh[qr * 64 + (ko ^ ((qr & 7) * 8))];
            bf16x8 wv = *(const bf16x8*)&wsh[vr * 64 + (ko ^ ((vr & 7) * 8))];
#pragma unroll
            for (int mt = 0; mt < 4; mt++) ka[mt] = mfma16(xf[mt], wk, ka[mt]);
#pragma unroll
            for (int mt = 0; mt < 4; mt++) qa[mt] = mfma16(xf[mt], wq, qa[mt]);
#pragma unroll
            for (int mt = 0; mt < 4; mt++) va[mt] = mfma16(wv, xf[mt], va[mt]);  // transposed
        }
    }
    __syncthreads();                             // staging LDS -> epilogue LDS reuse

    // C-layout: K/Q: row(tok)=quad*4+r, col(feat)=m16. V^T: row(feat)=quad*4+r, col(tok)=m16.
#pragma unroll
    for (int mt = 0; mt < 4; mt++) {
        int trow = mt * 16 + quad * 4;
#pragma unroll
        for (int r = 0; r < 4; r++) {
            co[(trow + r) * 136 + wave * 16 + m16]      = f2bf(ka[mt][r]);
            co[(trow + r) * 136 + 64 + wave * 16 + m16] = f2bf(qa[mt][r]);
            vco[wave * 1152 + (quad * 4 + r) * 72 + mt * 16 + m16] = f2bf(va[mt][r]);
        }
    }
    __syncthreads();
#pragma unroll
    for (int i = 0; i < 4; i++) {                // K/Q: 1024 b128 units, coalesced
        int u = tid + i * 256; int tok = u >> 4; int fg = u & 15;
        bf16x8 vv = *(const bf16x8*)&co[tok * 136 + fg * 8];
        unsigned short* dst = (fg < 8) ? Km : Qm;
        *(bf16x8*)&dst[(long)(row0 + tok) * 64 + (fg & 7) * 8] = vv;
    }
    int bb = row0 >> 11, tl = row0 & 2047;
#pragma unroll
    for (int i = 0; i < 2; i++) {                // V: b128 rows of Vt[b][h][t]
        int u = lane + i * 64; int hl = u >> 3; int tg = u & 7;
        bf16x8 vv = *(const bf16x8*)&vco[wave * 1152 + hl * 72 + tg * 8];
        *(bf16x8*)&Vt[((long)bb * 64 + wave * 16 + hl) * T_ + tl + tg * 8] = vv;
    }
}

// ---------------------------------------------------------------------------
// attn: flash attention, causal. Double-buffered K/V LDS, ONE barrier/iter,
// register prefetch of tile kt+1. Softmax denominator folded into PV via a
// constant ones-column B-fragment (5th accumulator) — no sum shuffles.
// ---------------------------------------------------------------------------
__global__ __launch_bounds__(256) void attn_kernel(
        const unsigned short* __restrict__ Qm, const unsigned short* __restrict__ Km,
        const unsigned short* __restrict__ Vt, const int* __restrict__ fe,
        float* __restrict__ out) {
    __shared__ __align__(16) unsigned short Klds[2][64 * 64];
    __shared__ __align__(16) unsigned short Vlds[2][64 * 64];
    __shared__ __align__(16) unsigned short Plds[4][16 * 64];

    int qt = (int)gridDim.x - 1 - blockIdx.x;    // longest blocks first
    int b = blockIdx.y;
    int tid = threadIdx.x, wave = tid >> 6, lane = tid & 63;
    int m16 = lane & 15, quad = lane >> 4;
    int row0 = qt * 64;
    long bT = (long)b * T_;

    int srow[2], sk8[2], ssw[2];
#pragma unroll
    for (int c = 0; c < 2; c++) {
        int cc = tid + c * 256;
        srow[c] = cc >> 3; sk8[c] = (cc & 7) * 8;
        ssw[c] = sk8[c] ^ ((srow[c] & 7) * 8);
    }

    const unsigned short* qp = Qm + (bT + row0 + wave * 16 + m16) * 64;
    bf16x8 qf0 = *(const bf16x8*)(qp + quad * 8);
    bf16x8 qf1 = *(const bf16x8*)(qp + 32 + quad * 8);

    f32x4 o[5];
#pragma unroll
    for (int h = 0; h < 5; h++) o[h] = (f32x4){0.f, 0.f, 0.f, 0.f};
    float mi[4];
#pragma unroll
    for (int r = 0; r < 4; r++) mi[r] = -INFINITY;
    int qloc = row0 + wave * 16 + quad * 4;

    bf16x8 onesb;                                // B-frag: col 0 = 1.0bf, rest 0
    {
        short ov = (m16 == 0) ? (short)0x3F80 : (short)0;
#pragma unroll
        for (int j = 0; j < 8; j++) onesb[j] = ov;
    }

    // preload tile 0 into regs and buf0
    bf16x8 kp[2], vp[2];
#pragma unroll
    for (int c = 0; c < 2; c++) {
        kp[c] = *(const bf16x8*)&Km[(bT + srow[c]) * 64 + sk8[c]];
        vp[c] = *(const bf16x8*)&Vt[((long)b * 64 + srow[c]) * T_ + sk8[c]];
    }
#pragma unroll
    for (int c = 0; c < 2; c++) {
        *(bf16x8*)&Klds[0][srow[c] * 64 + ssw[c]] = kp[c];
        *(bf16x8*)&Vlds[0][srow[c] * 64 + ssw[c]] = vp[c];
    }

    for (int kt = 0; kt <= qt; kt++) {
        int cur = kt & 1;
        if (kt < qt) {                           // prefetch tile kt+1
#pragma unroll
            for (int c = 0; c < 2; c++) {
                kp[c] = *(const bf16x8*)&Km[(bT + (kt + 1) * 64 + srow[c]) * 64 + sk8[c]];
                vp[c] = *(const bf16x8*)&Vt[((long)b * 64 + srow[c]) * T_ + (kt + 1) * 64 + sk8[c]];
            }
        }
        __syncthreads();                         // buf[cur] ready; prev reads done
        const unsigned short* Kb = Klds[cur];
        const unsigned short* Vb = Vlds[cur];

        f32x4 s[4];
#pragma unroll
        for (int ns = 0; ns < 4; ns++) {
            int krow = ns * 16 + m16;
            int swz = (krow & 7) * 8;
            bf16x8 kf0 = *(const bf16x8*)&Kb[krow * 64 + ((quad * 8) ^ swz)];
            bf16x8 kf1 = *(const bf16x8*)&Kb[krow * 64 + ((32 + quad * 8) ^ swz)];
            f32x4 z = (f32x4){0.f, 0.f, 0.f, 0.f};
            z = mfma16(qf0, kf0, z);
            z = mfma16(qf1, kf1, z);
            s[ns] = z;
        }

        bool diag = (kt == qt);
#pragma unroll
        for (int r = 0; r < 4; r++) {
            int qpos = qloc + r;
            if (diag) {
#pragma unroll
                for (int ns = 0; ns < 4; ns++) {
                    int n = kt * 64 + ns * 16 + m16;
                    if (n > qpos) s[ns][r] = -INFINITY;
                }
            }
            float mx = fmaxf(fmaxf(s[0][r], s[1][r]), fmaxf(s[2][r], s[3][r]));
            mx = fmaxf(mx, mi[r]);
#pragma unroll
            for (int off = 1; off < 16; off <<= 1)
                mx = fmaxf(mx, __shfl_xor(mx, off));
            float alpha = exp2f((mi[r] - mx) * LOG2E);
            mi[r] = mx;
#pragma unroll
            for (int ns = 0; ns < 4; ns++)
                s[ns][r] = exp2f((s[ns][r] - mx) * LOG2E);
#pragma unroll
            for (int h = 0; h < 5; h++) o[h][r] *= alpha;
        }

        // P -> LDS (C-layout -> A-layout), own-wave region
        unsigned short* pw = Plds[wave];
#pragma unroll
        for (int ns = 0; ns < 4; ns++)
#pragma unroll
            for (int r = 0; r < 4; r++) {
                int mrow = quad * 4 + r;
                int n = ns * 16 + m16;
                pw[mrow * 64 + (n ^ ((mrow & 7) * 8))] = f2bf(s[ns][r]);
            }

        int aswz = (m16 & 7) * 8;
        bf16x8 pa0 = *(const bf16x8*)&pw[m16 * 64 + ((quad * 8) ^ aswz)];
        bf16x8 pa1 = *(const bf16x8*)&pw[m16 * 64 + ((32 + quad * 8) ^ aswz)];
#pragma unroll
        for (int hs = 0; hs < 4; hs++) {
            int vrow = hs * 16 + m16;
            int vswz = (vrow & 7) * 8;
            bf16x8 vb0 = *(const bf16x8*)&Vb[vrow * 64 + ((quad * 8) ^ vswz)];
            bf16x8 vb1 = *(const bf16x8*)&Vb[vrow * 64 + ((32 + quad * 8) ^ vswz)];
            o[hs] = mfma16(pa0, vb0, o[hs]);
            o[hs] = mfma16(pa1, vb1, o[hs]);
        }
        o[4] = mfma16(pa0, onesb, o[4]);         // row-sum -> denominator
        o[4] = mfma16(pa1, onesb, o[4]);

        if (kt < qt) {                           // commit prefetched tile
            int nxt = 1 - cur;
#pragma unroll
            for (int c = 0; c < 2; c++) {
                *(bf16x8*)&Klds[nxt][srow[c] * 64 + ssw[c]] = kp[c];
                *(bf16x8*)&Vlds[nxt][srow[c] * 64 + ssw[c]] = vp[c];
            }
        }
    }

    int feb = fe[b];
#pragma unroll
    for (int r = 0; r < 4; r++) {
        int t = qloc + r;
        float l = __shfl(o[4][r], lane & 48);    // broadcast from m16==0 lane
        float inv = 1.0f / l;
        bool dead = (t >= feb);
#pragma unroll
        for (int hs = 0; hs < 4; hs++) {
            float val = dead ? __builtin_nanf("") : o[hs][r] * inv;
            out[(bT + t) * 64 + hs * 16 + m16] = val;
        }
    }
}

// ---------------------------------------------------------------------------
extern "C" void kernel_launch(void* const* d_in, const int* in_sizes, int n_in,
                              void* d_out, int out_size, void* d_ws, size_t ws_size,
                              hipStream_t stream) {
    const float* x  = (const float*)d_in[0];
    const float* Wk = (const float*)d_in[1];
    const float* Wq = (const float*)d_in[2];
    const float* Wv = (const float*)d_in[3];
    const int* idx  = (const int*)d_in[4];
    float* out = (float*)d_out;

    char* ws = (char*)d_ws;
    int* fe            = (int*)ws;                                 //    64 B
    unsigned short* Wt = (unsigned short*)(ws + 1024);             //  192 KiB
    unsigned short* Qm = (unsigned short*)(ws + 262144);           //    4 MiB
    unsigned short* Km = (unsigned short*)(ws + 262144 + 4194304); //    4 MiB
    unsigned short* Vt = (unsigned short*)(ws + 262144 + 8388608); //    4 MiB

    prep_kernel<<<385, 256, 0, stream>>>(Wk, Wq, Wv, Wt, fe);
    scan_kernel<<<128, 256, 0, stream>>>(idx, fe);
    qkv_kernel<<<512, 256, 0, stream>>>(x, Wt, Qm, Km, Vt);
    dim3 g(32, 16);
    attn_kernel<<<g, 256, 0, stream>>>(Qm, Km, Vt, fe, out);
}